// Round 1
// baseline (956.515 us; speedup 1.0000x reference)
//
#include <hip/hip_runtime.h>
#include <stdint.h>
#include <float.h>

// CRF forward-backward marginals. N=8192, C=1024, fp32.
//
// Segmented-chain architecture (no inter-block sync): 2048 segments/dir of
// SEGR=4 rows, warm-started GH=16 ghost rows early (validated R7: init error
// collapses to a per-segment constant; uniform shifts exactly invariant),
// constants resolved exactly via boundary-row LSE + prefix sum (stitch).
//
// R8: MFMA inner loop. Per block: G=16 chains == MFMA M=16. Per step, each
// block computes W(16x1024) x E(1024x1024) as 2048 v_mfma_f32_16x16x32_f16
// spread over 8 waves (wave owns 128 output columns). E is pre-packed in
// B-fragment order (lane = E[kt*32+quad*8+e][nt*16+li], 1KB frags, coalesced
// dwordx4 streams from L2, 2MB/CU/step = the memory floor). W is rebuilt in
// LDS each step (C-frag -> A-frag transpose, m118/m120 pattern):
// A[m=lane&15][k=quad*8+e], C/D[row=quad*4+reg][col=lane&15] (HW-verified).
// 2 barriers/step. Per-chain exact double offsets; f16 w/E (R6/R7-validated).

#define NR    8192
#define CC    1024
#define SEGR  4
#define GH    16
#define NSEG  2048    // per direction
#define TPB   512
#define G     16      // chains per block == MFMA M
#define NBLK  256
#define MAXT  (GH + SEGR - 1)   // 19

typedef _Float16 f16x8 __attribute__((ext_vector_type(8)));
typedef float    f32x4 __attribute__((ext_vector_type(4)));
typedef __fp16   hv2   __attribute__((ext_vector_type(2)));

__device__ __forceinline__ uint32_t packw(float a, float b) {
  hv2 r = __builtin_amdgcn_cvt_pkrtz(a, b);
  return __builtin_bit_cast(uint32_t, r);
}

// ---------------- prep 1: column maxes (fwd) and row maxes (bwd) ----------
__global__ __launch_bounds__(256) void crf_maxes(
    const float* __restrict__ T, float* __restrict__ Mc, float* __restrict__ Mr)
{
  const int bid = blockIdx.x, t = threadIdx.x;
  if (bid < 4) {                       // column maxes: thread per column
    const int j = bid * 256 + t;
    float m = -FLT_MAX;
    for (int k = 0; k < CC; ++k) m = fmaxf(m, T[(size_t)k * CC + j]);
    Mc[j] = m;
  } else {                             // row maxes: wave per row
    const int row = (bid - 4) * 4 + (t >> 6);
    const int lane = t & 63;
    const float* Tr = T + (size_t)row * CC;
    float m = -FLT_MAX;
    for (int i = lane; i < CC; i += 64) m = fmaxf(m, Tr[i]);
#pragma unroll
    for (int off = 32; off >= 1; off >>= 1) m = fmaxf(m, __shfl_xor(m, off, 64));
    if (lane == 0) Mr[row] = m;
  }
}

// ---------------- prep 2: pack E into MFMA B-fragment order ---------------
// frag fid = kt*64 + ntg (kt: 32 k-tiles of 32, ntg: 64 n-tiles of 16).
// lane holds 8 f16: E[kt*32 + (lane>>4)*8 + e][ntg*16 + (lane&15)], e=0..7.
// fwd: E[k][n] = exp(T[k][n] - Mc[n]); bwd: E[k][n] = exp(T[n][k] - Mr[n]).
__global__ __launch_bounds__(256) void crf_pack(
    const float* __restrict__ T, const float* __restrict__ Mc,
    const float* __restrict__ Mr, uint4* __restrict__ Ef, uint4* __restrict__ Eb)
{
  const int bid = blockIdx.x;          // 0..1023
  const int dir = bid >> 9;            // 0 fwd, 1 bwd
  const int tid = threadIdx.x;
  const int fid = ((bid & 511) << 2) + (tid >> 6);   // 0..2047
  const int lane = tid & 63;
  const int kt = fid >> 6, ntg = fid & 63;
  const int q = lane >> 4, li = lane & 15;
  const int n = ntg * 16 + li;
  const int kb = kt * 32 + q * 8;
  uint32_t o[4];
  if (dir == 0) {
    const float m = Mc[n];
#pragma unroll
    for (int p = 0; p < 4; ++p) {
      const float e0 = __expf(T[(size_t)(kb + 2 * p) * CC + n] - m);
      const float e1 = __expf(T[(size_t)(kb + 2 * p + 1) * CC + n] - m);
      o[p] = packw(e0, e1);
    }
    Ef[(size_t)fid * 64 + lane] = make_uint4(o[0], o[1], o[2], o[3]);
  } else {
    const float m = Mr[n];
    const float4 t0 = *(const float4*)&T[(size_t)n * CC + kb];
    const float4 t1 = *(const float4*)&T[(size_t)n * CC + kb + 4];
    o[0] = packw(__expf(t0.x - m), __expf(t0.y - m));
    o[1] = packw(__expf(t0.z - m), __expf(t0.w - m));
    o[2] = packw(__expf(t1.x - m), __expf(t1.y - m));
    o[3] = packw(__expf(t1.z - m), __expf(t1.w - m));
    Eb[(size_t)fid * 64 + lane] = make_uint4(o[0], o[1], o[2], o[3]);
  }
}

// ---------------- main: independent segment chains, MFMA ------------------
__global__ __launch_bounds__(TPB, 1) void crf_seg(
    const float* __restrict__ scores,
    const uint4* __restrict__ Ef, const uint4* __restrict__ Eb,
    const float* __restrict__ Mc, const float* __restrict__ Mr,
    float* __restrict__ out, float* __restrict__ qrows,
    double* __restrict__ OA, double* __restrict__ OB,
    double* __restrict__ eLf, double* __restrict__ gLf,
    double* __restrict__ eLb, double* __restrict__ gLb, int useQ)
{
  __shared__ unsigned short wh[G][CC + 8];   // A-matrix f16, +8 pad (33 KB)
  __shared__ float mgw[G][9];                // per-chain per-wave maxes
  __shared__ float lsw[G][9];                // boundary LSE partial sums

  const int bid  = blockIdx.x;
  const bool fwd = !(bid & 1);               // parity split across XCDs
  const int p    = bid >> 1;                 // 0..127
  const int tid  = threadIdx.x;
  const int wv   = tid >> 6;                 // wave 0..7
  const int lane = tid & 63;
  const int quad = lane >> 4, li = lane & 15;
  const int wbase = wv * 128;                // this wave's output-column base

  const uint4*  E    = fwd ? Ef : Eb;
  const float*  Mv   = fwd ? Mc : Mr;
  float*        emit = fwd ? out : qrows;
  double*       Oarr = fwd ? OA : OB;
  double*       eL   = fwd ? eLf : eLb;
  double*       gL   = fwd ? gLf : gLb;

  // geometry (block-uniform)
  int g0c[G], tEc[G], tendc[G];
#pragma unroll
  for (int c = 0; c < G; ++c) {
    const int s = G * p + c;
    if (fwd) {
      const int f = SEGR * s;
      const int gg = (f - GH) > 0 ? (f - GH) : 0;
      g0c[c] = gg; tEc[c] = f - gg; tendc[c] = f + SEGR - 1 - gg;
    } else {
      const int h = NR - 1 - SEGR * s;
      const int gg = (h + GH) < (NR - 1) ? (h + GH) : (NR - 1);
      g0c[c] = gg; tEc[c] = gg - h; tendc[c] = tEc[c] + SEGR - 1;
    }
  }

  float Mcol[8];
#pragma unroll
  for (int nt = 0; nt < 8; ++nt) Mcol[nt] = Mv[wbase + nt * 16 + li];

  // ---- init: pub = scores[g0] in C-frag layout pub[nt][reg] ----
  float pub[8][4];
#pragma unroll
  for (int reg = 0; reg < 4; ++reg) {
    const size_t rb = (size_t)g0c[quad * 4 + reg] * CC;
#pragma unroll
    for (int nt = 0; nt < 8; ++nt)
      pub[nt][reg] = scores[rb + wbase + nt * 16 + li];
  }
  double Off = 0.0;                          // thread c<16 tracks chain c
#pragma unroll
  for (int reg = 0; reg < 4; ++reg) {        // exact-start chains emit row g0
    const int c = quad * 4 + reg;
    if (tEc[c] == 0) {
      const size_t rb = (size_t)g0c[c] * CC;
#pragma unroll
      for (int nt = 0; nt < 8; ++nt) {
        const int j = wbase + nt * 16 + li;
        const float v = fwd ? 0.f : pub[nt][reg];
        if (useQ) emit[rb + j] = v;
        else if (!fwd) atomicAdd(&out[rb + j], v);
      }
    }
  }
  if (tid < G && tEc[tid] == 0) Oarr[g0c[tid]] = 0.0;

  const uint4* Eln = E + lane;

  for (int t = 1; t <= MAXT; ++t) {
    // (0) prefetch scores of produced rows
    float sc[8][4] = {};
#pragma unroll
    for (int reg = 0; reg < 4; ++reg) {
      const int c = quad * 4 + reg;
      if (t <= tendc[c]) {
        const size_t rb = (size_t)(fwd ? g0c[c] + t : g0c[c] - t) * CC;
#pragma unroll
        for (int nt = 0; nt < 8; ++nt)
          sc[nt][reg] = scores[rb + wbase + nt * 16 + li];
      }
    }

    // (A) per-chain block max of pub (= row t-1)
    float pm[4];
#pragma unroll
    for (int reg = 0; reg < 4; ++reg) {
      float m = pub[0][reg];
#pragma unroll
      for (int nt = 1; nt < 8; ++nt) m = fmaxf(m, pub[nt][reg]);
      m = fmaxf(m, __shfl_xor(m, 1, 64));
      m = fmaxf(m, __shfl_xor(m, 2, 64));
      m = fmaxf(m, __shfl_xor(m, 4, 64));
      m = fmaxf(m, __shfl_xor(m, 8, 64));   // quad holds its 4 chains' max
      pm[reg] = m;
    }
    if (li == 0) {
#pragma unroll
      for (int reg = 0; reg < 4; ++reg) mgw[quad * 4 + reg][wv] = pm[reg];
    }
    __syncthreads();                         // barrier A
    float mgli = mgw[li][0];
#pragma unroll
    for (int w = 1; w < 8; ++w) mgli = fmaxf(mgli, mgw[li][w]);
    float mg4[4];
#pragma unroll
    for (int reg = 0; reg < 4; ++reg) mg4[reg] = __shfl(mgli, quad * 4 + reg, 64);
    if (tid < G) Off += (double)mgli;        // Off = sum of maxes thru row t-1

    // boundary step? (block-uniform predicate)
    bool bstep = false;
#pragma unroll
    for (int c = 0; c < G; ++c)
      bstep = bstep || (t == tEc[c] && tEc[c] > 0) || (t - 1 == tendc[c]);
    if (bstep) {
      float s4[4];
#pragma unroll
      for (int reg = 0; reg < 4; ++reg) {
        float s = 0.f;
#pragma unroll
        for (int nt = 0; nt < 8; ++nt) s += __expf(pub[nt][reg] - mg4[reg]);
        s += __shfl_xor(s, 1, 64);
        s += __shfl_xor(s, 2, 64);
        s += __shfl_xor(s, 4, 64);
        s += __shfl_xor(s, 8, 64);
        s4[reg] = s;
      }
      if (li == 0) {
#pragma unroll
        for (int reg = 0; reg < 4; ++reg) lsw[quad * 4 + reg][wv] = s4[reg];
      }
    }

    // (B) w = exp(pub - mg) -> f16 -> A-matrix in LDS
#pragma unroll
    for (int reg = 0; reg < 4; ++reg) {
      const int row = quad * 4 + reg;
#pragma unroll
      for (int nt = 0; nt < 8; ++nt) {
        const __fp16 h = (__fp16)__expf(pub[nt][reg] - mg4[reg]);
        wh[row][wbase + nt * 16 + li] = __builtin_bit_cast(unsigned short, h);
      }
    }
    __syncthreads();                         // barrier B (covers lsw too)

    if (bstep && tid < G) {
      float s = lsw[tid][0];
#pragma unroll
      for (int w = 1; w < 8; ++w) s += lsw[tid][w];
      const double L = (double)__logf(s) + Off;   // LSE(row t-1) + offsets
      if (t == tEc[tid] && tEc[tid] > 0) gL[G * p + tid] = L;
      if (t - 1 == tendc[tid])           eL[G * p + tid] = L;
    }

    // (C) MFMA K-loop: D(16x128/wave) = W(16x1024) x E(1024x128)
    f32x4 acc[8];
#pragma unroll
    for (int nt = 0; nt < 8; ++nt) acc[nt] = (f32x4){0.f, 0.f, 0.f, 0.f};
#pragma unroll 2
    for (int kt = 0; kt < 32; ++kt) {
      const uint4 a4 = *(const uint4*)&wh[li][kt * 32 + quad * 8];
      const f16x8 af = __builtin_bit_cast(f16x8, a4);
#pragma unroll
      for (int nt = 0; nt < 8; ++nt) {
        const uint4 b4 = Eln[(size_t)(kt * 64 + wv * 8 + nt) * 64];
        acc[nt] = __builtin_amdgcn_mfma_f32_16x16x32_f16(
            af, __builtin_bit_cast(f16x8, b4), acc[nt], 0, 0, 0);
      }
    }

    // (D) update pub, emit real rows
#pragma unroll
    for (int reg = 0; reg < 4; ++reg) {
      const int c = quad * 4 + reg;
      if (t <= tendc[c]) {
        const size_t rb = (size_t)(fwd ? g0c[c] + t : g0c[c] - t) * CC;
        const bool em = (t >= tEc[c]);
#pragma unroll
        for (int nt = 0; nt < 8; ++nt) {
          const float pv = sc[nt][reg] + Mcol[nt] + __logf(acc[nt][reg]);
          pub[nt][reg] = pv;
          if (em) {
            const int j = wbase + nt * 16 + li;
            const float ov = fwd ? (pv - sc[nt][reg]) : pv;
            if (useQ) emit[rb + j] = ov;
            else atomicAdd(&out[rb + j], ov);
          }
        }
      }
    }
    if (tid < G && t >= tEc[tid] && t <= tendc[tid])
      Oarr[fwd ? g0c[tid] + t : g0c[tid] - t] = Off;
  }

  // ---- epilogue: eL for chains ending at row MAXT ----
  {
    float pm[4];
#pragma unroll
    for (int reg = 0; reg < 4; ++reg) {
      float m = pub[0][reg];
#pragma unroll
      for (int nt = 1; nt < 8; ++nt) m = fmaxf(m, pub[nt][reg]);
      m = fmaxf(m, __shfl_xor(m, 1, 64));
      m = fmaxf(m, __shfl_xor(m, 2, 64));
      m = fmaxf(m, __shfl_xor(m, 4, 64));
      m = fmaxf(m, __shfl_xor(m, 8, 64));
      pm[reg] = m;
    }
    if (li == 0) {
#pragma unroll
      for (int reg = 0; reg < 4; ++reg) mgw[quad * 4 + reg][wv] = pm[reg];
    }
    __syncthreads();
    float mgli = mgw[li][0];
#pragma unroll
    for (int w = 1; w < 8; ++w) mgli = fmaxf(mgli, mgw[li][w]);
    float mg4[4];
#pragma unroll
    for (int reg = 0; reg < 4; ++reg) mg4[reg] = __shfl(mgli, quad * 4 + reg, 64);
    if (tid < G) Off += (double)mgli;
    float s4[4];
#pragma unroll
    for (int reg = 0; reg < 4; ++reg) {
      float s = 0.f;
#pragma unroll
      for (int nt = 0; nt < 8; ++nt) s += __expf(pub[nt][reg] - mg4[reg]);
      s += __shfl_xor(s, 1, 64);
      s += __shfl_xor(s, 2, 64);
      s += __shfl_xor(s, 4, 64);
      s += __shfl_xor(s, 8, 64);
      s4[reg] = s;
    }
    if (li == 0) {
#pragma unroll
      for (int reg = 0; reg < 4; ++reg) lsw[quad * 4 + reg][wv] = s4[reg];
    }
    __syncthreads();
    if (tid < G && tendc[tid] == MAXT) {
      float s = lsw[tid][0];
#pragma unroll
      for (int w = 1; w < 8; ++w) s += lsw[tid][w];
      eL[G * p + tid] = (double)__logf(s) + Off;
    }
  }
}

// ---------------- stitch: prefix-sum segment constants + Z ----------------
__global__ __launch_bounds__(1024) void crf_stitch(
    const double* __restrict__ eLf, const double* __restrict__ gLf,
    const double* __restrict__ eLb, const double* __restrict__ gLb,
    double* __restrict__ CA, double* __restrict__ CB, double* __restrict__ Zd)
{
  __shared__ double sEf[NSEG], sGf[NSEG], sEb[NSEG], sGb[NSEG];  // 64 KB
  const int t = threadIdx.x;
  for (int i = t; i < NSEG; i += 1024) {
    sEf[i] = eLf[i]; sGf[i] = gLf[i]; sEb[i] = eLb[i]; sGb[i] = gLb[i];
  }
  __syncthreads();
  if (t == 0) {
    double c = 0.0; CA[0] = 0.0;
    for (int s = 1; s < NSEG; ++s) { c += sEf[s - 1] - sGf[s]; CA[s] = c; }
    *Zd = c + sEf[NSEG - 1];
  }
  if (t == 1) {
    double c = 0.0; CB[0] = 0.0;
    for (int s = 1; s < NSEG; ++s) { c += sEb[s - 1] - sGb[s]; CB[s] = c; }
  }
}

// ---------------- combine ------------------------------------------------
__global__ __launch_bounds__(256) void crf_combine(
    float* __restrict__ out, const float* __restrict__ qrows,
    const double* __restrict__ OA, const double* __restrict__ OB,
    const double* __restrict__ CA, const double* __restrict__ CB,
    const double* __restrict__ Zd, int useQ)
{
  const double Z = *Zd;
  const int g = blockIdx.x * 256 + threadIdx.x;   // [0, 2097152) float4s
  const int r = g >> 8;
  const float corr =
      (float)(OA[r] + CA[r >> 2] + OB[r] + CB[(NR - 1 - r) >> 2] - Z);
  float4 o = ((const float4*)out)[g];
  if (useQ) {
    const float4 q = ((const float4*)qrows)[g];
    o.x += q.x; o.y += q.y; o.z += q.z; o.w += q.w;
  }
  o.x += corr; o.y += corr; o.z += corr; o.w += corr;
  ((float4*)out)[g] = o;
}

extern "C" void kernel_launch(void* const* d_in, const int* in_sizes, int n_in,
                              void* d_out, int out_size, void* d_ws, size_t ws_size,
                              hipStream_t stream)
{
  const float* scores = (const float*)d_in[0];
  const float* T      = (const float*)d_in[1];
  float* out = (float*)d_out;
  char* w = (char*)d_ws;
  size_t off = 0;
  auto alloc = [&](size_t n) { char* q = w + off; off = (off + n + 255) & ~(size_t)255; return q; };

  uint4*  Ef = (uint4*)alloc((size_t)2048 * 1024);   // 2 MB (frag-packed)
  uint4*  Eb = (uint4*)alloc((size_t)2048 * 1024);   // 2 MB
  float*  Mc = (float*)alloc(CC * 4);
  float*  Mr = (float*)alloc(CC * 4);
  double* OA = (double*)alloc(NR * 8);
  double* OB = (double*)alloc(NR * 8);
  double* eLf = (double*)alloc(NSEG * 8);
  double* gLf = (double*)alloc(NSEG * 8);
  double* eLb = (double*)alloc(NSEG * 8);
  double* gLb = (double*)alloc(NSEG * 8);
  double* CA = (double*)alloc(NSEG * 8);
  double* CB = (double*)alloc(NSEG * 8);
  double* Zd = (double*)alloc(256);
  float*  qrows = (float*)alloc((size_t)NR * CC * 4);   // 32 MB
  const int useQ = (off <= ws_size) ? 1 : 0;

  if (!useQ)
    (void)hipMemsetAsync(out, 0, (size_t)NR * CC * 4, stream);
  crf_maxes<<<dim3(260), dim3(256), 0, stream>>>(T, Mc, Mr);
  crf_pack<<<dim3(1024), dim3(256), 0, stream>>>(T, Mc, Mr, Ef, Eb);
  crf_seg<<<dim3(NBLK), dim3(TPB), 0, stream>>>(scores, Ef, Eb, Mc, Mr, out,
                                                qrows, OA, OB, eLf, gLf, eLb,
                                                gLb, useQ);
  crf_stitch<<<dim3(1), dim3(1024), 0, stream>>>(eLf, gLf, eLb, gLb, CA, CB, Zd);
  crf_combine<<<dim3(8192), dim3(256), 0, stream>>>(out, qrows, OA, OB, CA, CB,
                                                    Zd, useQ);
}

// Round 2
// 725.438 us; speedup vs baseline: 1.3185x; 1.3185x over previous
//
#include <hip/hip_runtime.h>
#include <stdint.h>
#include <float.h>

// CRF forward-backward marginals. N=8192, C=1024, fp32.
//
// Segmented-chain architecture (no inter-block sync): 2048 segments/dir of
// SEGR=4 rows, warm-started GH=16 ghost rows early, constants resolved
// exactly via boundary-row LSE + prefix sum (stitch).
//
// R8: MFMA inner loop; E pre-packed in B-fragment order, streamed from L2.
// R9: (a) TPB 512->1024 — 16 waves x 64 output cols (4 frags/wave/kt),
//     4 waves/SIMD for L2-latency hiding (was 2); (b) per-block kt rotation
//     (bid>>3)&31 decorrelates the 32 same-XCD CUs' L2 address streams
//     (blocks on one XCD all read the same 2MB E per step in lockstep
//     otherwise -> transient L2 hot-banking). K-sum reorder only (fp32,
//     positive terms) — numerically negligible.

#define NR    8192
#define CC    1024
#define SEGR  4
#define GH    16
#define NSEG  2048    // per direction
#define TPB   1024
#define NWV   16      // waves per block
#define G     16      // chains per block == MFMA M
#define NBLK  256
#define MAXT  (GH + SEGR - 1)   // 19

typedef _Float16 f16x8 __attribute__((ext_vector_type(8)));
typedef float    f32x4 __attribute__((ext_vector_type(4)));
typedef __fp16   hv2   __attribute__((ext_vector_type(2)));

__device__ __forceinline__ uint32_t packw(float a, float b) {
  hv2 r = __builtin_amdgcn_cvt_pkrtz(a, b);
  return __builtin_bit_cast(uint32_t, r);
}

// ---------------- prep 1: column maxes (fwd) and row maxes (bwd) ----------
__global__ __launch_bounds__(256) void crf_maxes(
    const float* __restrict__ T, float* __restrict__ Mc, float* __restrict__ Mr)
{
  const int bid = blockIdx.x, t = threadIdx.x;
  if (bid < 4) {                       // column maxes: thread per column
    const int j = bid * 256 + t;
    float m = -FLT_MAX;
    for (int k = 0; k < CC; ++k) m = fmaxf(m, T[(size_t)k * CC + j]);
    Mc[j] = m;
  } else {                             // row maxes: wave per row
    const int row = (bid - 4) * 4 + (t >> 6);
    const int lane = t & 63;
    const float* Tr = T + (size_t)row * CC;
    float m = -FLT_MAX;
    for (int i = lane; i < CC; i += 64) m = fmaxf(m, Tr[i]);
#pragma unroll
    for (int off = 32; off >= 1; off >>= 1) m = fmaxf(m, __shfl_xor(m, off, 64));
    if (lane == 0) Mr[row] = m;
  }
}

// ---------------- prep 2: pack E into MFMA B-fragment order ---------------
// frag fid = kt*64 + ntg (kt: 32 k-tiles of 32, ntg: 64 n-tiles of 16).
// lane holds 8 f16: E[kt*32 + (lane>>4)*8 + e][ntg*16 + (lane&15)], e=0..7.
// fwd: E[k][n] = exp(T[k][n] - Mc[n]); bwd: E[k][n] = exp(T[n][k] - Mr[n]).
__global__ __launch_bounds__(256) void crf_pack(
    const float* __restrict__ T, const float* __restrict__ Mc,
    const float* __restrict__ Mr, uint4* __restrict__ Ef, uint4* __restrict__ Eb)
{
  const int bid = blockIdx.x;          // 0..1023
  const int dir = bid >> 9;            // 0 fwd, 1 bwd
  const int tid = threadIdx.x;
  const int fid = ((bid & 511) << 2) + (tid >> 6);   // 0..2047
  const int lane = tid & 63;
  const int kt = fid >> 6, ntg = fid & 63;
  const int q = lane >> 4, li = lane & 15;
  const int n = ntg * 16 + li;
  const int kb = kt * 32 + q * 8;
  uint32_t o[4];
  if (dir == 0) {
    const float m = Mc[n];
#pragma unroll
    for (int p = 0; p < 4; ++p) {
      const float e0 = __expf(T[(size_t)(kb + 2 * p) * CC + n] - m);
      const float e1 = __expf(T[(size_t)(kb + 2 * p + 1) * CC + n] - m);
      o[p] = packw(e0, e1);
    }
    Ef[(size_t)fid * 64 + lane] = make_uint4(o[0], o[1], o[2], o[3]);
  } else {
    const float m = Mr[n];
    const float4 t0 = *(const float4*)&T[(size_t)n * CC + kb];
    const float4 t1 = *(const float4*)&T[(size_t)n * CC + kb + 4];
    o[0] = packw(__expf(t0.x - m), __expf(t0.y - m));
    o[1] = packw(__expf(t0.z - m), __expf(t0.w - m));
    o[2] = packw(__expf(t1.x - m), __expf(t1.y - m));
    o[3] = packw(__expf(t1.z - m), __expf(t1.w - m));
    Eb[(size_t)fid * 64 + lane] = make_uint4(o[0], o[1], o[2], o[3]);
  }
}

// ---------------- main: independent segment chains, MFMA ------------------
__global__ __launch_bounds__(TPB, 1) void crf_seg(
    const float* __restrict__ scores,
    const uint4* __restrict__ Ef, const uint4* __restrict__ Eb,
    const float* __restrict__ Mc, const float* __restrict__ Mr,
    float* __restrict__ out, float* __restrict__ qrows,
    double* __restrict__ OA, double* __restrict__ OB,
    double* __restrict__ eLf, double* __restrict__ gLf,
    double* __restrict__ eLb, double* __restrict__ gLb, int useQ)
{
  __shared__ unsigned short wh[G][CC + 8];   // A-matrix f16, +8 pad (33 KB)
  __shared__ float mgw[G][NWV + 1];          // per-chain per-wave maxes
  __shared__ float lsw[G][NWV + 1];          // boundary LSE partial sums

  const int bid  = blockIdx.x;
  const bool fwd = !(bid & 1);               // parity split across XCDs
  const int p    = bid >> 1;                 // 0..127
  const int tid  = threadIdx.x;
  const int wv   = tid >> 6;                 // wave 0..15
  const int lane = tid & 63;
  const int quad = lane >> 4, li = lane & 15;
  const int wbase = wv * 64;                 // this wave's output-column base
  const int rot  = (bid >> 3) & 31;          // per-XCD-resident kt rotation

  const uint4*  E    = fwd ? Ef : Eb;
  const float*  Mv   = fwd ? Mc : Mr;
  float*        emit = fwd ? out : qrows;
  double*       Oarr = fwd ? OA : OB;
  double*       eL   = fwd ? eLf : eLb;
  double*       gL   = fwd ? gLf : gLb;

  // geometry (block-uniform)
  int g0c[G], tEc[G], tendc[G];
#pragma unroll
  for (int c = 0; c < G; ++c) {
    const int s = G * p + c;
    if (fwd) {
      const int f = SEGR * s;
      const int gg = (f - GH) > 0 ? (f - GH) : 0;
      g0c[c] = gg; tEc[c] = f - gg; tendc[c] = f + SEGR - 1 - gg;
    } else {
      const int h = NR - 1 - SEGR * s;
      const int gg = (h + GH) < (NR - 1) ? (h + GH) : (NR - 1);
      g0c[c] = gg; tEc[c] = gg - h; tendc[c] = tEc[c] + SEGR - 1;
    }
  }

  float Mcol[4];
#pragma unroll
  for (int nt = 0; nt < 4; ++nt) Mcol[nt] = Mv[wbase + nt * 16 + li];

  // ---- init: pub = scores[g0] in C-frag layout pub[nt][reg] ----
  float pub[4][4];
#pragma unroll
  for (int reg = 0; reg < 4; ++reg) {
    const size_t rb = (size_t)g0c[quad * 4 + reg] * CC;
#pragma unroll
    for (int nt = 0; nt < 4; ++nt)
      pub[nt][reg] = scores[rb + wbase + nt * 16 + li];
  }
  double Off = 0.0;                          // thread c<16 tracks chain c
#pragma unroll
  for (int reg = 0; reg < 4; ++reg) {        // exact-start chains emit row g0
    const int c = quad * 4 + reg;
    if (tEc[c] == 0) {
      const size_t rb = (size_t)g0c[c] * CC;
#pragma unroll
      for (int nt = 0; nt < 4; ++nt) {
        const int j = wbase + nt * 16 + li;
        const float v = fwd ? 0.f : pub[nt][reg];
        if (useQ) emit[rb + j] = v;
        else if (!fwd) atomicAdd(&out[rb + j], v);
      }
    }
  }
  if (tid < G && tEc[tid] == 0) Oarr[g0c[tid]] = 0.0;

  const uint4* Eln = E + lane;

  for (int t = 1; t <= MAXT; ++t) {
    // (0) prefetch scores of produced rows
    float sc[4][4] = {};
#pragma unroll
    for (int reg = 0; reg < 4; ++reg) {
      const int c = quad * 4 + reg;
      if (t <= tendc[c]) {
        const size_t rb = (size_t)(fwd ? g0c[c] + t : g0c[c] - t) * CC;
#pragma unroll
        for (int nt = 0; nt < 4; ++nt)
          sc[nt][reg] = scores[rb + wbase + nt * 16 + li];
      }
    }

    // (A) per-chain block max of pub (= row t-1)
    float pm[4];
#pragma unroll
    for (int reg = 0; reg < 4; ++reg) {
      float m = pub[0][reg];
#pragma unroll
      for (int nt = 1; nt < 4; ++nt) m = fmaxf(m, pub[nt][reg]);
      m = fmaxf(m, __shfl_xor(m, 1, 64));
      m = fmaxf(m, __shfl_xor(m, 2, 64));
      m = fmaxf(m, __shfl_xor(m, 4, 64));
      m = fmaxf(m, __shfl_xor(m, 8, 64));   // quad holds its 4 chains' max
      pm[reg] = m;
    }
    if (li == 0) {
#pragma unroll
      for (int reg = 0; reg < 4; ++reg) mgw[quad * 4 + reg][wv] = pm[reg];
    }
    __syncthreads();                         // barrier A
    float mgli = mgw[li][0];
#pragma unroll
    for (int w = 1; w < NWV; ++w) mgli = fmaxf(mgli, mgw[li][w]);
    float mg4[4];
#pragma unroll
    for (int reg = 0; reg < 4; ++reg) mg4[reg] = __shfl(mgli, quad * 4 + reg, 64);
    if (tid < G) Off += (double)mgli;        // Off = sum of maxes thru row t-1

    // boundary step? (block-uniform predicate)
    bool bstep = false;
#pragma unroll
    for (int c = 0; c < G; ++c)
      bstep = bstep || (t == tEc[c] && tEc[c] > 0) || (t - 1 == tendc[c]);
    if (bstep) {
      float s4[4];
#pragma unroll
      for (int reg = 0; reg < 4; ++reg) {
        float s = 0.f;
#pragma unroll
        for (int nt = 0; nt < 4; ++nt) s += __expf(pub[nt][reg] - mg4[reg]);
        s += __shfl_xor(s, 1, 64);
        s += __shfl_xor(s, 2, 64);
        s += __shfl_xor(s, 4, 64);
        s += __shfl_xor(s, 8, 64);
        s4[reg] = s;
      }
      if (li == 0) {
#pragma unroll
        for (int reg = 0; reg < 4; ++reg) lsw[quad * 4 + reg][wv] = s4[reg];
      }
    }

    // (B) w = exp(pub - mg) -> f16 -> A-matrix in LDS
#pragma unroll
    for (int reg = 0; reg < 4; ++reg) {
      const int row = quad * 4 + reg;
#pragma unroll
      for (int nt = 0; nt < 4; ++nt) {
        const __fp16 h = (__fp16)__expf(pub[nt][reg] - mg4[reg]);
        wh[row][wbase + nt * 16 + li] = __builtin_bit_cast(unsigned short, h);
      }
    }
    __syncthreads();                         // barrier B (covers lsw too)

    if (bstep && tid < G) {
      float s = lsw[tid][0];
#pragma unroll
      for (int w = 1; w < NWV; ++w) s += lsw[tid][w];
      const double L = (double)__logf(s) + Off;   // LSE(row t-1) + offsets
      if (t == tEc[tid] && tEc[tid] > 0) gL[G * p + tid] = L;
      if (t - 1 == tendc[tid])           eL[G * p + tid] = L;
    }

    // (C) MFMA K-loop: D(16x64/wave) = W(16x1024) x E(1024x64)
    // kt rotated per block to decorrelate same-XCD L2 streams.
    f32x4 acc[4];
#pragma unroll
    for (int nt = 0; nt < 4; ++nt) acc[nt] = (f32x4){0.f, 0.f, 0.f, 0.f};
#pragma unroll 2
    for (int kt = 0; kt < 32; ++kt) {
      const int ktr = (kt + rot) & 31;
      const uint4 a4 = *(const uint4*)&wh[li][ktr * 32 + quad * 8];
      const f16x8 af = __builtin_bit_cast(f16x8, a4);
#pragma unroll
      for (int nt = 0; nt < 4; ++nt) {
        const uint4 b4 = Eln[(size_t)(ktr * 64 + wv * 4 + nt) * 64];
        acc[nt] = __builtin_amdgcn_mfma_f32_16x16x32_f16(
            af, __builtin_bit_cast(f16x8, b4), acc[nt], 0, 0, 0);
      }
    }

    // (D) update pub, emit real rows
#pragma unroll
    for (int reg = 0; reg < 4; ++reg) {
      const int c = quad * 4 + reg;
      if (t <= tendc[c]) {
        const size_t rb = (size_t)(fwd ? g0c[c] + t : g0c[c] - t) * CC;
        const bool em = (t >= tEc[c]);
#pragma unroll
        for (int nt = 0; nt < 4; ++nt) {
          const float pv = sc[nt][reg] + Mcol[nt] + __logf(acc[nt][reg]);
          pub[nt][reg] = pv;
          if (em) {
            const int j = wbase + nt * 16 + li;
            const float ov = fwd ? (pv - sc[nt][reg]) : pv;
            if (useQ) emit[rb + j] = ov;
            else atomicAdd(&out[rb + j], ov);
          }
        }
      }
    }
    if (tid < G && t >= tEc[tid] && t <= tendc[tid])
      Oarr[fwd ? g0c[tid] + t : g0c[tid] - t] = Off;
  }

  // ---- epilogue: eL for chains ending at row MAXT ----
  {
    float pm[4];
#pragma unroll
    for (int reg = 0; reg < 4; ++reg) {
      float m = pub[0][reg];
#pragma unroll
      for (int nt = 1; nt < 4; ++nt) m = fmaxf(m, pub[nt][reg]);
      m = fmaxf(m, __shfl_xor(m, 1, 64));
      m = fmaxf(m, __shfl_xor(m, 2, 64));
      m = fmaxf(m, __shfl_xor(m, 4, 64));
      m = fmaxf(m, __shfl_xor(m, 8, 64));
      pm[reg] = m;
    }
    if (li == 0) {
#pragma unroll
      for (int reg = 0; reg < 4; ++reg) mgw[quad * 4 + reg][wv] = pm[reg];
    }
    __syncthreads();
    float mgli = mgw[li][0];
#pragma unroll
    for (int w = 1; w < NWV; ++w) mgli = fmaxf(mgli, mgw[li][w]);
    float mg4[4];
#pragma unroll
    for (int reg = 0; reg < 4; ++reg) mg4[reg] = __shfl(mgli, quad * 4 + reg, 64);
    if (tid < G) Off += (double)mgli;
    float s4[4];
#pragma unroll
    for (int reg = 0; reg < 4; ++reg) {
      float s = 0.f;
#pragma unroll
      for (int nt = 0; nt < 4; ++nt) s += __expf(pub[nt][reg] - mg4[reg]);
      s += __shfl_xor(s, 1, 64);
      s += __shfl_xor(s, 2, 64);
      s += __shfl_xor(s, 4, 64);
      s += __shfl_xor(s, 8, 64);
      s4[reg] = s;
    }
    if (li == 0) {
#pragma unroll
      for (int reg = 0; reg < 4; ++reg) lsw[quad * 4 + reg][wv] = s4[reg];
    }
    __syncthreads();
    if (tid < G && tendc[tid] == MAXT) {
      float s = lsw[tid][0];
#pragma unroll
      for (int w = 1; w < NWV; ++w) s += lsw[tid][w];
      eL[G * p + tid] = (double)__logf(s) + Off;
    }
  }
}

// ---------------- stitch: prefix-sum segment constants + Z ----------------
__global__ __launch_bounds__(1024) void crf_stitch(
    const double* __restrict__ eLf, const double* __restrict__ gLf,
    const double* __restrict__ eLb, const double* __restrict__ gLb,
    double* __restrict__ CA, double* __restrict__ CB, double* __restrict__ Zd)
{
  __shared__ double sEf[NSEG], sGf[NSEG], sEb[NSEG], sGb[NSEG];  // 64 KB
  const int t = threadIdx.x;
  for (int i = t; i < NSEG; i += 1024) {
    sEf[i] = eLf[i]; sGf[i] = gLf[i]; sEb[i] = eLb[i]; sGb[i] = gLb[i];
  }
  __syncthreads();
  if (t == 0) {
    double c = 0.0; CA[0] = 0.0;
    for (int s = 1; s < NSEG; ++s) { c += sEf[s - 1] - sGf[s]; CA[s] = c; }
    *Zd = c + sEf[NSEG - 1];
  }
  if (t == 1) {
    double c = 0.0; CB[0] = 0.0;
    for (int s = 1; s < NSEG; ++s) { c += sEb[s - 1] - sGb[s]; CB[s] = c; }
  }
}

// ---------------- combine ------------------------------------------------
__global__ __launch_bounds__(256) void crf_combine(
    float* __restrict__ out, const float* __restrict__ qrows,
    const double* __restrict__ OA, const double* __restrict__ OB,
    const double* __restrict__ CA, const double* __restrict__ CB,
    const double* __restrict__ Zd, int useQ)
{
  const double Z = *Zd;
  const int g = blockIdx.x * 256 + threadIdx.x;   // [0, 2097152) float4s
  const int r = g >> 8;
  const float corr =
      (float)(OA[r] + CA[r >> 2] + OB[r] + CB[(NR - 1 - r) >> 2] - Z);
  float4 o = ((const float4*)out)[g];
  if (useQ) {
    const float4 q = ((const float4*)qrows)[g];
    o.x += q.x; o.y += q.y; o.z += q.z; o.w += q.w;
  }
  o.x += corr; o.y += corr; o.z += corr; o.w += corr;
  ((float4*)out)[g] = o;
}

extern "C" void kernel_launch(void* const* d_in, const int* in_sizes, int n_in,
                              void* d_out, int out_size, void* d_ws, size_t ws_size,
                              hipStream_t stream)
{
  const float* scores = (const float*)d_in[0];
  const float* T      = (const float*)d_in[1];
  float* out = (float*)d_out;
  char* w = (char*)d_ws;
  size_t off = 0;
  auto alloc = [&](size_t n) { char* q = w + off; off = (off + n + 255) & ~(size_t)255; return q; };

  uint4*  Ef = (uint4*)alloc((size_t)2048 * 1024);   // 2 MB (frag-packed)
  uint4*  Eb = (uint4*)alloc((size_t)2048 * 1024);   // 2 MB
  float*  Mc = (float*)alloc(CC * 4);
  float*  Mr = (float*)alloc(CC * 4);
  double* OA = (double*)alloc(NR * 8);
  double* OB = (double*)alloc(NR * 8);
  double* eLf = (double*)alloc(NSEG * 8);
  double* gLf = (double*)alloc(NSEG * 8);
  double* eLb = (double*)alloc(NSEG * 8);
  double* gLb = (double*)alloc(NSEG * 8);
  double* CA = (double*)alloc(NSEG * 8);
  double* CB = (double*)alloc(NSEG * 8);
  double* Zd = (double*)alloc(256);
  float*  qrows = (float*)alloc((size_t)NR * CC * 4);   // 32 MB
  const int useQ = (off <= ws_size) ? 1 : 0;

  if (!useQ)
    (void)hipMemsetAsync(out, 0, (size_t)NR * CC * 4, stream);
  crf_maxes<<<dim3(260), dim3(256), 0, stream>>>(T, Mc, Mr);
  crf_pack<<<dim3(1024), dim3(256), 0, stream>>>(T, Mc, Mr, Ef, Eb);
  crf_seg<<<dim3(NBLK), dim3(TPB), 0, stream>>>(scores, Ef, Eb, Mc, Mr, out,
                                                qrows, OA, OB, eLf, gLf, eLb,
                                                gLb, useQ);
  crf_stitch<<<dim3(1), dim3(1024), 0, stream>>>(eLf, gLf, eLb, gLb, CA, CB, Zd);
  crf_combine<<<dim3(8192), dim3(256), 0, stream>>>(out, qrows, OA, OB, CA, CB,
                                                    Zd, useQ);
}